// Round 7
// baseline (245.898 us; speedup 1.0000x reference)
//
#include <hip/hip_runtime.h>
#include <hip/hip_bf16.h>

typedef short v8s __attribute__((ext_vector_type(8)));
typedef float v4f __attribute__((ext_vector_type(4)));
typedef float v16f __attribute__((ext_vector_type(16)));
typedef __hip_bfloat16 bf16;

__device__ __forceinline__ float b2f(bf16 h) { return __bfloat162float(h); }
__device__ __forceinline__ bf16 f2b(float f) { return __float2bfloat16(f); }

// Q pre-scale: hd^-0.5 * log2(e) so softmax runs in exp2 domain with no muls.
#define QSCALE 0.18033688f

// Async global->LDS, 16 B/lane; dest = lds base + lane*16 (wave-uniform base).
__device__ __forceinline__ void gll16(const void* g, void* l) {
    __builtin_amdgcn_global_load_lds(
        (const __attribute__((address_space(1))) void*)g,
        (__attribute__((address_space(3))) void*)l, 16, 0, 0);
}

// Pack two f32 -> one u32 of 2 bf16 (src0 -> low16, src1 -> high16).
__device__ __forceinline__ unsigned cvtpk(float lo, float hi_) {
    unsigned r;
    asm("v_cvt_pk_bf16_f32 %0, %1, %2" : "=v"(r) : "v"(lo), "v"(hi_));
    return r;
}

// v_permlane32_swap_b32: a[32:63] <-> b[0:31].
// After: a = [a_lo | b_lo], b = [a_hi | b_hi].
__device__ __forceinline__ void pl32swap(unsigned& a, unsigned& b) {
    asm("v_permlane32_swap_b32 %0, %1" : "+v"(a), "+v"(b));
}

// ---------------------------------------------------------------------------
// Fused GroupNorm + transpose, BOTH tensors in one dispatch (z selects).
// Reads fp32 src[b][c][l], writes bf16 dstT[b][l][c].  One block per (b,g,z).
// v2: output phase reads 8x ds_read_b128 (8ch x 8l tile) + in-register
// halfword transpose, replacing the 64 scalar ds_read_u16 per thread.
// ---------------------------------------------------------------------------
__global__ __launch_bounds__(256) void gn_t_kernel(
    const float* __restrict__ x, const float* __restrict__ ctx,
    const float* __restrict__ qw, const float* __restrict__ qb,
    const float* __restrict__ kw, const float* __restrict__ kb,
    bf16* __restrict__ xnT, bf16* __restrict__ cnT)
{
    const int b = blockIdx.y, g = blockIdx.x, z = blockIdx.z, c0 = g * 16;
    const float* src = z ? ctx : x;
    const float* gw  = z ? kw : qw;
    const float* gb  = z ? kb : qb;
    bf16* dst = z ? cnT : xnT;
    __shared__ __attribute__((aligned(16))) bf16 lx[16][1032];
    __shared__ float rS[4], rQ[4];
    __shared__ float sSc[16], sSh[16];
    const int t = threadIdx.x, wave = t >> 6, lane = t & 63;
    const float* xb = src + ((long)b * 512 + c0) * 1024;
    float sum = 0.f, sq = 0.f;
#pragma unroll
    for (int i = 0; i < 16; i++) {
        int q = t + i * 256;              // 4096 float4s over 16x1024
        int ci = q >> 8, l0 = (q & 255) * 4;
        float4 v = *(const float4*)(xb + (long)ci * 1024 + l0);
        sum += v.x + v.y + v.z + v.w;
        sq  += v.x * v.x + v.y * v.y + v.z * v.z + v.w * v.w;
        union { short4 s4v; bf16 h[4]; } w;
        w.h[0] = f2b(v.x); w.h[1] = f2b(v.y); w.h[2] = f2b(v.z); w.h[3] = f2b(v.w);
        *(short4*)&lx[ci][l0] = w.s4v;
    }
#pragma unroll
    for (int off = 32; off > 0; off >>= 1) {
        sum += __shfl_down(sum, off);
        sq  += __shfl_down(sq, off);
    }
    if (lane == 0) { rS[wave] = sum; rQ[wave] = sq; }
    __syncthreads();
    if (t < 16) {
        float S = rS[0] + rS[1] + rS[2] + rS[3];
        float Q = rQ[0] + rQ[1] + rQ[2] + rQ[3];
        const float inv_n = 1.f / 16384.f;
        float mean = S * inv_n;
        float var  = Q * inv_n - mean * mean;
        float rstd = rsqrtf(var + 1e-5f);
        float w = gw[c0 + t];
        sSc[t] = rstd * w;
        sSh[t] = gb[c0 + t] - mean * rstd * w;
    }
    __syncthreads();
    // output: thread owns channel-half hf (8 ch) x 8 l; vector LDS reads +
    // in-register transpose; store pattern identical to v1 (lane pairs cover
    // 32 B contiguous then 1024 B jump).
    {
        const int hf = t & 1, lg = t >> 1;
        const int ch0 = hf * 8, l0 = lg * 8;
        v8s rd[8];
#pragma unroll
        for (int r = 0; r < 8; r++)
            rd[r] = *(const v8s*)&lx[ch0 + r][l0];
        float sc[8], sh[8];
#pragma unroll
        for (int r = 0; r < 8; r++) { sc[r] = sSc[ch0 + r]; sh[r] = sSh[ch0 + r]; }
#pragma unroll
        for (int j = 0; j < 8; j++) {
            union { float4 f4; bf16 h[8]; } o_;
#pragma unroll
            for (int r = 0; r < 8; r++) {
                union { short s; bf16 h; } cv; cv.s = rd[r][j];
                o_.h[r] = f2b(b2f(cv.h) * sc[r] + sh[r]);
            }
            *(float4*)(dst + ((long)b * 1024 + l0 + j) * 512 + c0 + ch0) = o_.f4;
        }
    }
}

// ---------------------------------------------------------------------------
// Weight fp32 -> bf16 conversion (cqw 256K, ckvw 512K, pw 256K elements).
// ---------------------------------------------------------------------------
__global__ __launch_bounds__(256) void wconv_kernel(
    const float* __restrict__ a, const float* __restrict__ bsrc,
    const float* __restrict__ csrc, bf16* __restrict__ oa,
    bf16* __restrict__ ob, bf16* __restrict__ oc)
{
    int id = blockIdx.x * 256 + threadIdx.x;     // [0, 262144) float4 units
    const float* src; bf16* dst; int off;
    if (id < 65536)       { src = a;    dst = oa; off = id; }
    else if (id < 196608) { src = bsrc; dst = ob; off = id - 65536; }
    else                  { src = csrc; dst = oc; off = id - 196608; }
    float4 v = ((const float4*)src)[off];
    union { short4 s4v; bf16 h[4]; } w;
    w.h[0] = f2b(v.x); w.h[1] = f2b(v.y); w.h[2] = f2b(v.z); w.h[3] = f2b(v.w);
    ((short4*)dst)[off] = w.s4v;
}

// ---------------------------------------------------------------------------
// Fused Q/K/V GEMM v2.  1D grid, XCD-grouped decode: batch bz pinned to XCD
// bz&7 so all three ops of a batch (xnT 1MB + cnT 1MB + weights 1.5MB) stay
// resident in that XCD's 4MB L2.
//  op0: QT[l][o] = (xnT·wQ^T  + cqb)·QSCALE    M=1024 N=512
//  op1: KT[l][o] =  cnT·wKV[:512]^T + ckvbK    M=1024 N=512
//  op2: V [o][l] =  wKV[512:]·cnT^T + ckvbV    M=512  N=1024 (bias per M)
// K-loop: 2-phase double-buffered LDS, one barrier per K-step, prefetch
// before compute, vmcnt(0) drain after compute.
// ---------------------------------------------------------------------------
__global__ __launch_bounds__(256) void qkv_gemm_kernel(
    const bf16* __restrict__ xnT, const bf16* __restrict__ cnT,
    const bf16* __restrict__ wQ, const bf16* __restrict__ wKV,
    bf16* __restrict__ QT, bf16* __restrict__ KT, bf16* __restrict__ Vo,
    const float* __restrict__ cqb, const float* __restrict__ ckvb)
{
    const long PB = 512L * 1024;
    const int blk = blockIdx.x;
    const int xcd = blk & 7, idx = blk >> 3;       // idx in [0,192)
    const int half = idx / 96, rr = idx % 96;
    const int op = rr >> 5, bx = rr & 31;          // 3 ops x 32 tiles
    const int bz = xcd + 8 * half;                 // batch pinned to xcd
    const bf16* A; const bf16* B; bf16* C; const float* bias;
    int nBlkN, N, biasPerM; float scale;
    if (op == 0) {
        A = xnT + bz * PB; B = wQ;  C = QT + bz * PB; bias = cqb;
        nBlkN = 4; N = 512; biasPerM = 0; scale = QSCALE;
    } else if (op == 1) {
        A = cnT + bz * PB; B = wKV; C = KT + bz * PB; bias = ckvb;
        nBlkN = 4; N = 512; biasPerM = 0; scale = 1.0f;
    } else {
        A = wKV + 512L * 512; B = cnT + bz * PB; C = Vo + bz * PB; bias = ckvb + 512;
        nBlkN = 8; N = 1024; biasPerM = 1; scale = 1.0f;
    }
    const int m0 = (bx / nBlkN) * 128, n0 = (bx % nBlkN) * 128;
    __shared__ __attribute__((aligned(16))) bf16 lA[2][128][64];
    __shared__ __attribute__((aligned(16))) bf16 lB[2][128][64];
    const int t = threadIdx.x, wave = t >> 6, lane = t & 63;
    const int quad = lane >> 4, c = lane & 15;
    const int wm = (wave >> 1) * 64, wn = (wave & 1) * 64;
    const int rIS = lane >> 3;                 // row within 8-row segment
    const int chG = (lane & 7) ^ rIS;          // source-side XOR swizzle
    const bf16* Ag[4]; const bf16* Bg[4]; int segr[4];
#pragma unroll
    for (int j = 0; j < 4; j++) {
        int seg = wave + j * 4;                // 16 segments x 8 rows
        segr[j] = seg * 8;
        Ag[j] = A + (long)(m0 + segr[j] + rIS) * 512 + chG * 8;
        Bg[j] = B + (long)(n0 + segr[j] + rIS) * 512 + chG * 8;
    }
    auto issue = [&](int k0, int bi) {
#pragma unroll
        for (int j = 0; j < 4; j++) {
            gll16(Ag[j] + k0, &lA[bi][segr[j]][0]);
            gll16(Bg[j] + k0, &lB[bi][segr[j]][0]);
        }
    };
    v4f acc[4][4] = {};
    issue(0, 0);                               // prologue prefetch
    for (int kc = 0; kc < 8; kc++) {
        const int cur = kc & 1;
        asm volatile("s_waitcnt vmcnt(0)" ::: "memory");
        __builtin_amdgcn_s_barrier();
        __builtin_amdgcn_sched_barrier(0);
        if (kc < 7) issue((kc + 1) * 64, cur ^ 1);
#pragma unroll
        for (int kk = 0; kk < 2; kk++) {
            v8s af[4], bfr[4];
#pragma unroll
            for (int mt = 0; mt < 4; mt++)
                af[mt] = *(const v8s*)&lA[cur][wm + mt * 16 + c][((kk * 4 + quad) ^ (c & 7)) * 8];
#pragma unroll
            for (int nt = 0; nt < 4; nt++)
                bfr[nt] = *(const v8s*)&lB[cur][wn + nt * 16 + c][((kk * 4 + quad) ^ (c & 7)) * 8];
#pragma unroll
            for (int mt = 0; mt < 4; mt++)
#pragma unroll
                for (int nt = 0; nt < 4; nt++)
                    acc[mt][nt] = __builtin_amdgcn_mfma_f32_16x16x32_bf16(
                        af[mt], bfr[nt], acc[mt][nt], 0, 0, 0);
        }
    }
#pragma unroll
    for (int mt = 0; mt < 4; mt++) {
#pragma unroll
        for (int nt = 0; nt < 4; nt++) {
#pragma unroll
            for (int r = 0; r < 4; r++) {
                int row = m0 + wm + mt * 16 + quad * 4 + r;
                int col = n0 + wn + nt * 16 + c;
                float v = (acc[mt][nt][r] + (biasPerM ? bias[row] : bias[col])) * scale;
                C[(long)row * N + col] = f2b(v);
            }
        }
    }
}

// ---------------------------------------------------------------------------
// Projection GEMM v2: out[b][o][l] = pw·AOT^T + pb + x (fp32 out + resid).
// 2-phase double-buffer (free at this grid's 2 blocks/CU); XCD-pinned decode.
// ---------------------------------------------------------------------------
__global__ __launch_bounds__(256) void gemm_proj_kernel(
    const bf16* __restrict__ A,
    const bf16* __restrict__ B, long sBb,
    float* __restrict__ C,
    const float* __restrict__ bias,
    const float* __restrict__ resid,
    int M, int N)
{
    const int blk = blockIdx.x;
    const int xcd = blk & 7, idx = blk >> 3;       // idx in [0,64)
    const int bz = xcd + 8 * (idx & 1);            // batch pinned to xcd
    const int tile = idx >> 1;                     // [0,32): 4 m x 8 n
    const int m0 = (tile >> 3) * 128, n0 = (tile & 7) * 128;
    const bf16* Bb = B + (long)bz * sBb;
    __shared__ __attribute__((aligned(16))) bf16 lA[2][128][64];
    __shared__ __attribute__((aligned(16))) bf16 lB[2][128][64];
    const int t = threadIdx.x, wave = t >> 6, lane = t & 63;
    const int quad = lane >> 4, c = lane & 15;
    const int wm = (wave >> 1) * 64, wn = (wave & 1) * 64;
    const int rIS = lane >> 3, chG = (lane & 7) ^ rIS;
    const bf16* Ag[4]; const bf16* Bg[4]; int segr[4];
#pragma unroll
    for (int j = 0; j < 4; j++) {
        int seg = wave + j * 4;
        segr[j] = seg * 8;
        Ag[j] = A + (long)(m0 + segr[j] + rIS) * 512 + chG * 8;
        Bg[j] = Bb + (long)(n0 + segr[j] + rIS) * 512 + chG * 8;
    }
    auto issue = [&](int k0, int bi) {
#pragma unroll
        for (int j = 0; j < 4; j++) {
            gll16(Ag[j] + k0, &lA[bi][segr[j]][0]);
            gll16(Bg[j] + k0, &lB[bi][segr[j]][0]);
        }
    };
    v4f acc[4][4] = {};
    issue(0, 0);
    for (int kc = 0; kc < 8; kc++) {
        const int cur = kc & 1;
        asm volatile("s_waitcnt vmcnt(0)" ::: "memory");
        __builtin_amdgcn_s_barrier();
        __builtin_amdgcn_sched_barrier(0);
        if (kc < 7) issue((kc + 1) * 64, cur ^ 1);
#pragma unroll
        for (int kk = 0; kk < 2; kk++) {
            v8s af[4], bfr[4];
#pragma unroll
            for (int mt = 0; mt < 4; mt++)
                af[mt] = *(const v8s*)&lA[cur][wm + mt * 16 + c][((kk * 4 + quad) ^ (c & 7)) * 8];
#pragma unroll
            for (int nt = 0; nt < 4; nt++)
                bfr[nt] = *(const v8s*)&lB[cur][wn + nt * 16 + c][((kk * 4 + quad) ^ (c & 7)) * 8];
#pragma unroll
            for (int mt = 0; mt < 4; mt++)
#pragma unroll
                for (int nt = 0; nt < 4; nt++)
                    acc[mt][nt] = __builtin_amdgcn_mfma_f32_16x16x32_bf16(
                        af[mt], bfr[nt], acc[mt][nt], 0, 0, 0);
        }
    }
#pragma unroll
    for (int mt = 0; mt < 4; mt++) {
#pragma unroll
        for (int nt = 0; nt < 4; nt++) {
#pragma unroll
            for (int r = 0; r < 4; r++) {
                int row = m0 + wm + mt * 16 + quad * 4 + r;
                int col = n0 + wn + nt * 16 + c;
                float v = acc[mt][nt][r] + bias[row]
                        + resid[(long)bz * ((long)M * N) + (long)row * N + col];
                C[(long)bz * ((long)M * N) + (long)row * N + col] = v;
            }
        }
    }
}

// ---------------------------------------------------------------------------
// Flash attention v5: 32x32x16 swapped QK^T, in-register softmax (T12),
// 32 i-rows/wave (128-row blocks), counted-vmcnt pipeline, phase-merged QK,
// setprio.  TLP doubled vs v4: LDS 40 KB (K 3-deep, V 2-deep buffers) ->
// 4 blocks/CU, grid 1024 = exactly 4x256 (16 waves/CU, 4/SIMD, no tail).
// vmcnt discipline: per iter issue V(jt+1) THEN K(jt+2); single vmcnt(2)
// before the barrier retires {K(jt), V(jt)} and keeps K(jt+1) in flight --
// never drains to 0.  V gets 1 full iter to land, K gets 2.
// XCD decode: 8 i-blocks of one (b,h) on one XCD; K/V stays L2-resident.
// QT/KT: bf16 [b][l][h*64+d] (Q pre-scaled); V: bf16 [b][h*64+d][l].
// Out AOT[b][i][h*64+d]; aliases QT (block reads only its own rows).
// ---------------------------------------------------------------------------
__global__ __launch_bounds__(256, 4) void attn_kernel(
    const bf16* QT, const bf16* __restrict__ KT,
    const bf16* __restrict__ V, bf16* AOT)
{
    const int nblk = blockIdx.x;
    const int s = nblk >> 3;
    const int it = s & 7;                          // 8 i-blocks of 128 rows
    const int g = ((s >> 3) << 3) | (nblk & 7);    // (b,h) group in [0,128)
    const int h = g & 7, b = g >> 3;
    const int i0 = it * 128;
    __shared__ __attribute__((aligned(16))) bf16 lk[3][64][64];
    __shared__ __attribute__((aligned(16))) bf16 lv[2][64][64];
    const int t = threadIdx.x, wave = t >> 6, lane = t & 63;
    const int m31 = lane & 31, hi = lane >> 5;
    const int rIS = lane >> 3, chG = (lane & 7) ^ rIS;
    // Q -> regs, B-frag layout: lane holds Q[i = m31][k = ks*16+hi*8+e]
    const bf16* Qb = QT + ((long)b * 1024 + i0 + wave * 32 + m31) * 512 + h * 64;
    v8s qf[4];
#pragma unroll
    for (int ks = 0; ks < 4; ks++)
        qf[ks] = *(const v8s*)(Qb + ks * 16 + hi * 8);
    // K/V staging bases: 8 segments each, 2 per wave (source-side XOR swizzle)
    const bf16* Kg[2]; const bf16* Vg[2];
#pragma unroll
    for (int j = 0; j < 2; j++) {
        int seg = wave * 2 + j;
        Kg[j] = KT + ((long)b * 1024 + seg * 8 + rIS) * 512 + h * 64 + chG * 8;
        Vg[j] = V + ((long)b * 512 + h * 64 + seg * 8 + rIS) * 1024 + chG * 8;
    }
    auto issueK = [&](int jtx, int bi) {
#pragma unroll
        for (int j = 0; j < 2; j++)
            gll16(Kg[j] + (long)jtx * 64 * 512, &lk[bi][(wave * 2 + j) * 8][0]);
    };
    auto issueV = [&](int jtx, int bi) {
#pragma unroll
        for (int j = 0; j < 2; j++)
            gll16(Vg[j] + (long)jtx * 64, &lv[bi][(wave * 2 + j) * 8][0]);
    };
    // prologue (order matters for vmcnt): V(0), K(0), K(1)
    issueV(0, 0);
    issueK(0, 0);
    issueK(1, 1);
    float lsum = 0.f;
    v16f o0 = {}, o1 = {};

// SM(jb) + PV(jb): consumes sj (S^T regs) for one j-half of 32 columns.
#define SMPV(sj, JB)                                                           \
    {                                                                          \
        unsigned u[8];                                                         \
        _Pragma("unroll")                                                      \
        for (int k2 = 0; k2 < 8; k2++) {                                       \
            float pl = __builtin_amdgcn_exp2f(sj[2 * k2]);                     \
            float ph = __builtin_amdgcn_exp2f(sj[2 * k2 + 1]);                 \
            lsum += pl + ph;                                                   \
            u[k2] = cvtpk(pl, ph);                                             \
        }                                                                      \
        pl32swap(u[0], u[2]); pl32swap(u[1], u[3]);                            \
        pl32swap(u[4], u[6]); pl32swap(u[5], u[7]);                            \
        __builtin_amdgcn_s_setprio(1);                                         \
        _Pragma("unroll")                                                      \
        for (int kk = 0; kk < 2; kk++) {                                       \
            union { unsigned w[4]; v8s v; } pf;                                \
            pf.w[0] = u[4 * kk + 0]; pf.w[1] = u[4 * kk + 1];                  \
            pf.w[2] = u[4 * kk + 2]; pf.w[3] = u[4 * kk + 3];                  \
            const int cc2 = ((JB) * 2 + kk) * 2 + hi;                          \
            v8s vf0 = *(const v8s*)&lv[vcur][m31][(cc2 ^ (m31 & 7)) * 8];      \
            o0 = __builtin_amdgcn_mfma_f32_32x32x16_bf16(vf0, pf.v, o0, 0, 0, 0); \
            v8s vf1 = *(const v8s*)&lv[vcur][32 + m31][(cc2 ^ (m31 & 7)) * 8]; \
            o1 = __builtin_amdgcn_mfma_f32_32x32x16_bf16(vf1, pf.v, o1, 0, 0, 0); \
        }                                                                      \
        __builtin_amdgcn_s_setprio(0);                                         \
    }

    for (int jt = 0; jt < 16; jt++) {
        const int kcur = jt % 3, vcur = jt & 1;
        // retire {K(jt), V(jt)}; keep K(jt+1)'s 2 loads in flight
        asm volatile("s_waitcnt vmcnt(2)" ::: "memory");
        __builtin_amdgcn_s_barrier();
        __builtin_amdgcn_sched_barrier(0);
        // prefetch: V(jt+1) first (1-iter landing), then K(jt+2) (2-iter)
        issueV((jt + 1) & 15, vcur ^ 1);
        issueK((jt + 2) & 15, (jt + 2) % 3);
        // ---- QK both j-halves: 2 independent 4-deep MFMA chains ----
        v16f s0 = {}, s1 = {};
        __builtin_amdgcn_s_setprio(1);
#pragma unroll
        for (int ks = 0; ks < 4; ks++) {
            const int chs = ((ks * 2 + hi) ^ (m31 & 7)) * 8;
            v8s kf0 = *(const v8s*)&lk[kcur][m31][chs];
            v8s kf1 = *(const v8s*)&lk[kcur][32 + m31][chs];
            s0 = __builtin_amdgcn_mfma_f32_32x32x16_bf16(kf0, qf[ks], s0, 0, 0, 0);
            s1 = __builtin_amdgcn_mfma_f32_32x32x16_bf16(kf1, qf[ks], s1, 0, 0, 0);
        }
        __builtin_amdgcn_s_setprio(0);
        // ---- SM0 -> PV0 -> SM1 -> PV1 (SM1 fills PV0's MFMA shadow) ----
        SMPV(s0, 0)
        SMPV(s1, 1)
    }
#undef SMPV
    // epilogue: combine half-wave partial sums, normalize, store
    {
        float lt = lsum + __shfl_xor(lsum, 32);
        float inv = 1.f / lt;
        bf16* Ob = AOT + ((long)b * 1024 + i0 + wave * 32 + m31) * 512 + h * 64;
#pragma unroll
        for (int gq = 0; gq < 4; gq++) {
            union { short4 s4v; bf16 hh[4]; } w0, w1;
#pragma unroll
            for (int k = 0; k < 4; k++) {
                w0.hh[k] = f2b(o0[gq * 4 + k] * inv);
                w1.hh[k] = f2b(o1[gq * 4 + k] * inv);
            }
            *(short4*)(Ob + gq * 8 + hi * 4)      = w0.s4v;
            *(short4*)(Ob + 32 + gq * 8 + hi * 4) = w1.s4v;
        }
    }
}

// ---------------------------------------------------------------------------
extern "C" void kernel_launch(void* const* d_in, const int* in_sizes, int n_in,
                              void* d_out, int out_size, void* d_ws, size_t ws_size,
                              hipStream_t stream)
{
    const float* x    = (const float*)d_in[0];
    const float* ctx  = (const float*)d_in[1];
    const float* nqw  = (const float*)d_in[2];
    const float* nqb  = (const float*)d_in[3];
    const float* nkw  = (const float*)d_in[4];
    const float* nkb  = (const float*)d_in[5];
    const float* cqw  = (const float*)d_in[6];
    const float* cqb  = (const float*)d_in[7];
    const float* ckvw = (const float*)d_in[8];
    const float* ckvb = (const float*)d_in[9];
    const float* pw   = (const float*)d_in[10];
    const float* pb   = (const float*)d_in[11];
    float* out = (float*)d_out;
    bf16* ws  = (bf16*)d_ws;

    const long PB  = 512L * 1024;     // per-batch elements
    const long TOT = 16L * PB;        // per-tensor elements (16 MiB bf16)
    bf16* s0 = ws;                    // xnT [b][l][c]
    bf16* s1 = ws + TOT;              // cnT [b][l][c]
    bf16* s2 = ws + 2 * TOT;          // QT; attn writes AOT in place
    bf16* s3 = ws + 3 * TOT;          // KT
    bf16* s4 = ws + 4 * TOT;          // V [b][o][l]
    bf16* wQ  = ws + 5 * TOT;         // 262144
    bf16* wKV = wQ + 262144;          // 524288
    bf16* wP  = wKV + 524288;         // 262144
    // ws use: 80 MiB + 2 MiB

    dim3 blk(256);
    gn_t_kernel<<<dim3(32, 16, 2), blk, 0, stream>>>(
        x, ctx, nqw, nqb, nkw, nkb, s0, s1);
    wconv_kernel<<<dim3(1024), blk, 0, stream>>>(cqw, ckvw, pw, wQ, wKV, wP);
    // fused Q/K/V GEMMs; 1536 blocks, XCD-grouped 1D decode
    qkv_gemm_kernel<<<dim3(1536), blk, 0, stream>>>(
        s0, s1, wQ, wKV, s2, s3, s4, cqb, ckvb);
    // attention (AOT in place over QT); 1024 blocks, XCD-grouped decode
    attn_kernel<<<dim3(1024), blk, 0, stream>>>(s2, s3, s4, s2);
    // out[b][o][l] = wP·AOT^T + pb + x   (fp32); 512 blocks, XCD-pinned
    gemm_proj_kernel<<<dim3(512), blk, 0, stream>>>(
        wP, s2, PB, out, pb, x, 512, 1024);
}

// Round 8
// 237.106 us; speedup vs baseline: 1.0371x; 1.0371x over previous
//
#include <hip/hip_runtime.h>
#include <hip/hip_bf16.h>

typedef short v8s __attribute__((ext_vector_type(8)));
typedef float v4f __attribute__((ext_vector_type(4)));
typedef float v16f __attribute__((ext_vector_type(16)));
typedef __hip_bfloat16 bf16;

__device__ __forceinline__ float b2f(bf16 h) { return __bfloat162float(h); }
__device__ __forceinline__ bf16 f2b(float f) { return __float2bfloat16(f); }

// Q pre-scale: hd^-0.5 * log2(e) so softmax runs in exp2 domain with no muls.
#define QSCALE 0.18033688f

// Async global->LDS, 16 B/lane; dest = lds base + lane*16 (wave-uniform base).
__device__ __forceinline__ void gll16(const void* g, void* l) {
    __builtin_amdgcn_global_load_lds(
        (const __attribute__((address_space(1))) void*)g,
        (__attribute__((address_space(3))) void*)l, 16, 0, 0);
}

// Pack two f32 -> one u32 of 2 bf16 (src0 -> low16, src1 -> high16).
__device__ __forceinline__ unsigned cvtpk(float lo, float hi_) {
    unsigned r;
    asm("v_cvt_pk_bf16_f32 %0, %1, %2" : "=v"(r) : "v"(lo), "v"(hi_));
    return r;
}

// v_permlane32_swap_b32: a[32:63] <-> b[0:31].
// After: a = [a_lo | b_lo], b = [a_hi | b_hi].
__device__ __forceinline__ void pl32swap(unsigned& a, unsigned& b) {
    asm("v_permlane32_swap_b32 %0, %1" : "+v"(a), "+v"(b));
}

// ---------------------------------------------------------------------------
// Fused GroupNorm + transpose, BOTH tensors in one dispatch (z selects).
// Reads fp32 src[b][c][l], writes bf16 dstT[b][l][c].  One block per (b,g,z).
// ---------------------------------------------------------------------------
__global__ __launch_bounds__(256) void gn_t_kernel(
    const float* __restrict__ x, const float* __restrict__ ctx,
    const float* __restrict__ qw, const float* __restrict__ qb,
    const float* __restrict__ kw, const float* __restrict__ kb,
    bf16* __restrict__ xnT, bf16* __restrict__ cnT)
{
    const int b = blockIdx.y, g = blockIdx.x, z = blockIdx.z, c0 = g * 16;
    const float* src = z ? ctx : x;
    const float* gw  = z ? kw : qw;
    const float* gb  = z ? kb : qb;
    bf16* dst = z ? cnT : xnT;
    __shared__ __attribute__((aligned(16))) bf16 lx[16][1032];
    __shared__ float rS[4], rQ[4];
    __shared__ float sSc[16], sSh[16];
    const int t = threadIdx.x, wave = t >> 6, lane = t & 63;
    const float* xb = src + ((long)b * 512 + c0) * 1024;
    float sum = 0.f, sq = 0.f;
#pragma unroll
    for (int i = 0; i < 16; i++) {
        int q = t + i * 256;              // 4096 float4s over 16x1024
        int ci = q >> 8, l0 = (q & 255) * 4;
        float4 v = *(const float4*)(xb + (long)ci * 1024 + l0);
        sum += v.x + v.y + v.z + v.w;
        sq  += v.x * v.x + v.y * v.y + v.z * v.z + v.w * v.w;
        union { short4 s4v; bf16 h[4]; } w;
        w.h[0] = f2b(v.x); w.h[1] = f2b(v.y); w.h[2] = f2b(v.z); w.h[3] = f2b(v.w);
        *(short4*)&lx[ci][l0] = w.s4v;
    }
#pragma unroll
    for (int off = 32; off > 0; off >>= 1) {
        sum += __shfl_down(sum, off);
        sq  += __shfl_down(sq, off);
    }
    if (lane == 0) { rS[wave] = sum; rQ[wave] = sq; }
    __syncthreads();
    if (t < 16) {
        float S = rS[0] + rS[1] + rS[2] + rS[3];
        float Q = rQ[0] + rQ[1] + rQ[2] + rQ[3];
        const float inv_n = 1.f / 16384.f;
        float mean = S * inv_n;
        float var  = Q * inv_n - mean * mean;
        float rstd = rsqrtf(var + 1e-5f);
        float w = gw[c0 + t];
        sSc[t] = rstd * w;
        sSh[t] = gb[c0 + t] - mean * rstd * w;
    }
    __syncthreads();
    // output: thread owns channel-half hf (8 ch) x 8 l; vector LDS reads +
    // in-register transpose.
    {
        const int hf = t & 1, lg = t >> 1;
        const int ch0 = hf * 8, l0 = lg * 8;
        v8s rd[8];
#pragma unroll
        for (int r = 0; r < 8; r++)
            rd[r] = *(const v8s*)&lx[ch0 + r][l0];
        float sc[8], sh[8];
#pragma unroll
        for (int r = 0; r < 8; r++) { sc[r] = sSc[ch0 + r]; sh[r] = sSh[ch0 + r]; }
#pragma unroll
        for (int j = 0; j < 8; j++) {
            union { float4 f4; bf16 h[8]; } o_;
#pragma unroll
            for (int r = 0; r < 8; r++) {
                union { short s; bf16 h; } cv; cv.s = rd[r][j];
                o_.h[r] = f2b(b2f(cv.h) * sc[r] + sh[r]);
            }
            *(float4*)(dst + ((long)b * 1024 + l0 + j) * 512 + c0 + ch0) = o_.f4;
        }
    }
}

// ---------------------------------------------------------------------------
// Weight fp32 -> bf16 conversion (cqw 256K, ckvw 512K, pw 256K elements).
// ---------------------------------------------------------------------------
__global__ __launch_bounds__(256) void wconv_kernel(
    const float* __restrict__ a, const float* __restrict__ bsrc,
    const float* __restrict__ csrc, bf16* __restrict__ oa,
    bf16* __restrict__ ob, bf16* __restrict__ oc)
{
    int id = blockIdx.x * 256 + threadIdx.x;     // [0, 262144) float4 units
    const float* src; bf16* dst; int off;
    if (id < 65536)       { src = a;    dst = oa; off = id; }
    else if (id < 196608) { src = bsrc; dst = ob; off = id - 65536; }
    else                  { src = csrc; dst = oc; off = id - 196608; }
    float4 v = ((const float4*)src)[off];
    union { short4 s4v; bf16 h[4]; } w;
    w.h[0] = f2b(v.x); w.h[1] = f2b(v.y); w.h[2] = f2b(v.z); w.h[3] = f2b(v.w);
    ((short4*)dst)[off] = w.s4v;
}

// ---------------------------------------------------------------------------
// Fused Q/K/V GEMM v3: the R4-verified counted-vmcnt pipeline, with TLP kept.
// BK=32 tiles [128][32] -> 3 buffers = 48 KB -> 3 blocks/CU (12 waves/CU),
// vmcnt(4) retires step kc's 4 loads while kc+1's stay in flight (2-step
// lookahead, never drains).  Conflict-free 32-col swizzle:
//   write: lane l of seg writes phys chunk (l&3) at row seg*16+(l>>2),
//          fetching logical chunk (l&3)^(r&3)^((r>>2)&1)  [r = l>>2]
//   read:  logical chunk q at row R -> phys chunk q^(c&3)^((c>>2)&1)
//   (16 lanes -> 8 distinct 16B slots x2 = 2-way = free)
// XCD-grouped decode unchanged (batch pinned to XCD, L2-resident operands).
// ---------------------------------------------------------------------------
__global__ __launch_bounds__(256) void qkv_gemm_kernel(
    const bf16* __restrict__ xnT, const bf16* __restrict__ cnT,
    const bf16* __restrict__ wQ, const bf16* __restrict__ wKV,
    bf16* __restrict__ QT, bf16* __restrict__ KT, bf16* __restrict__ Vo,
    const float* __restrict__ cqb, const float* __restrict__ ckvb)
{
    const long PB = 512L * 1024;
    const int blk = blockIdx.x;
    const int xcd = blk & 7, idx = blk >> 3;       // idx in [0,192)
    const int half = idx / 96, rr = idx % 96;
    const int op = rr >> 5, bx = rr & 31;          // 3 ops x 32 tiles
    const int bz = xcd + 8 * half;                 // batch pinned to xcd
    const bf16* A; const bf16* B; bf16* C; const float* bias;
    int nBlkN, N, biasPerM; float scale;
    if (op == 0) {
        A = xnT + bz * PB; B = wQ;  C = QT + bz * PB; bias = cqb;
        nBlkN = 4; N = 512; biasPerM = 0; scale = QSCALE;
    } else if (op == 1) {
        A = cnT + bz * PB; B = wKV; C = KT + bz * PB; bias = ckvb;
        nBlkN = 4; N = 512; biasPerM = 0; scale = 1.0f;
    } else {
        A = wKV + 512L * 512; B = cnT + bz * PB; C = Vo + bz * PB; bias = ckvb + 512;
        nBlkN = 8; N = 1024; biasPerM = 1; scale = 1.0f;
    }
    const int m0 = (bx / nBlkN) * 128, n0 = (bx % nBlkN) * 128;
    __shared__ __attribute__((aligned(16))) bf16 lA[3][128][32];
    __shared__ __attribute__((aligned(16))) bf16 lB[3][128][32];
    const int t = threadIdx.x, wave = t >> 6, lane = t & 63;
    const int quad = lane >> 4, c = lane & 15;
    const int wm = (wave >> 1) * 64, wn = (wave & 1) * 64;
    // staging: 8 segments of 16 rows; wave handles segs wave*2, wave*2+1
    const int r16 = lane >> 2;                     // row within segment
    const int c4 = lane & 3;                       // physical chunk
    const int cswz = c4 ^ (r16 & 3) ^ ((r16 >> 2) & 1);  // logical chunk
    const bf16* Ag[2]; const bf16* Bg[2];
#pragma unroll
    for (int j = 0; j < 2; j++) {
        int seg = wave * 2 + j;
        Ag[j] = A + (long)(m0 + seg * 16 + r16) * 512 + cswz * 8;
        Bg[j] = B + (long)(n0 + seg * 16 + r16) * 512 + cswz * 8;
    }
    auto issue = [&](int k0, int bi) {
#pragma unroll
        for (int j = 0; j < 2; j++) {
            gll16(Ag[j] + k0, &lA[bi][(wave * 2 + j) * 16][0]);
            gll16(Bg[j] + k0, &lB[bi][(wave * 2 + j) * 16][0]);
        }
    };
    v4f acc[4][4] = {};
    issue(0, 0);          // 2-deep prologue: 8 loads in flight per wave
    issue(32, 1);
    const int rdsw = (quad ^ (c & 3) ^ ((c >> 2) & 1)) * 8;  // read chunk
    for (int kc = 0; kc < 16; kc++) {
        const int cur = kc % 3;
        // retire step kc's 4 loads (issued 2 steps ago); keep kc+1's in flight
        asm volatile("s_waitcnt vmcnt(4)" ::: "memory");
        __builtin_amdgcn_s_barrier();
        __builtin_amdgcn_sched_barrier(0);
        // prefetch kc+2 (wraps redundantly at 16,17 -> keeps vmcnt exact)
        issue(((kc + 2) & 15) * 32, (kc + 2) % 3);
        v8s af[4], bfr[4];
#pragma unroll
        for (int mt = 0; mt < 4; mt++)
            af[mt] = *(const v8s*)&lA[cur][wm + mt * 16 + c][rdsw];
#pragma unroll
        for (int nt = 0; nt < 4; nt++)
            bfr[nt] = *(const v8s*)&lB[cur][wn + nt * 16 + c][rdsw];
#pragma unroll
        for (int mt = 0; mt < 4; mt++)
#pragma unroll
            for (int nt = 0; nt < 4; nt++)
                acc[mt][nt] = __builtin_amdgcn_mfma_f32_16x16x32_bf16(
                    af[mt], bfr[nt], acc[mt][nt], 0, 0, 0);
    }
#pragma unroll
    for (int mt = 0; mt < 4; mt++) {
#pragma unroll
        for (int nt = 0; nt < 4; nt++) {
#pragma unroll
            for (int r = 0; r < 4; r++) {
                int row = m0 + wm + mt * 16 + quad * 4 + r;
                int col = n0 + wn + nt * 16 + c;
                float v = (acc[mt][nt][r] + (biasPerM ? bias[row] : bias[col])) * scale;
                C[(long)row * N + col] = f2b(v);
            }
        }
    }
}

// ---------------------------------------------------------------------------
// Projection GEMM v2: out[b][o][l] = pw·AOT^T + pb + x (fp32 out + resid).
// 2-phase double-buffer (free at this grid's 2 blocks/CU); XCD-pinned decode.
// ---------------------------------------------------------------------------
__global__ __launch_bounds__(256) void gemm_proj_kernel(
    const bf16* __restrict__ A,
    const bf16* __restrict__ B, long sBb,
    float* __restrict__ C,
    const float* __restrict__ bias,
    const float* __restrict__ resid,
    int M, int N)
{
    const int blk = blockIdx.x;
    const int xcd = blk & 7, idx = blk >> 3;       // idx in [0,64)
    const int bz = xcd + 8 * (idx & 1);            // batch pinned to xcd
    const int tile = idx >> 1;                     // [0,32): 4 m x 8 n
    const int m0 = (tile >> 3) * 128, n0 = (tile & 7) * 128;
    const bf16* Bb = B + (long)bz * sBb;
    __shared__ __attribute__((aligned(16))) bf16 lA[2][128][64];
    __shared__ __attribute__((aligned(16))) bf16 lB[2][128][64];
    const int t = threadIdx.x, wave = t >> 6, lane = t & 63;
    const int quad = lane >> 4, c = lane & 15;
    const int wm = (wave >> 1) * 64, wn = (wave & 1) * 64;
    const int rIS = lane >> 3, chG = (lane & 7) ^ rIS;
    const bf16* Ag[4]; const bf16* Bg[4]; int segr[4];
#pragma unroll
    for (int j = 0; j < 4; j++) {
        int seg = wave + j * 4;
        segr[j] = seg * 8;
        Ag[j] = A + (long)(m0 + segr[j] + rIS) * 512 + chG * 8;
        Bg[j] = Bb + (long)(n0 + segr[j] + rIS) * 512 + chG * 8;
    }
    auto issue = [&](int k0, int bi) {
#pragma unroll
        for (int j = 0; j < 4; j++) {
            gll16(Ag[j] + k0, &lA[bi][segr[j]][0]);
            gll16(Bg[j] + k0, &lB[bi][segr[j]][0]);
        }
    };
    v4f acc[4][4] = {};
    issue(0, 0);
    for (int kc = 0; kc < 8; kc++) {
        const int cur = kc & 1;
        asm volatile("s_waitcnt vmcnt(0)" ::: "memory");
        __builtin_amdgcn_s_barrier();
        __builtin_amdgcn_sched_barrier(0);
        if (kc < 7) issue((kc + 1) * 64, cur ^ 1);
#pragma unroll
        for (int kk = 0; kk < 2; kk++) {
            v8s af[4], bfr[4];
#pragma unroll
            for (int mt = 0; mt < 4; mt++)
                af[mt] = *(const v8s*)&lA[cur][wm + mt * 16 + c][((kk * 4 + quad) ^ (c & 7)) * 8];
#pragma unroll
            for (int nt = 0; nt < 4; nt++)
                bfr[nt] = *(const v8s*)&lB[cur][wn + nt * 16 + c][((kk * 4 + quad) ^ (c & 7)) * 8];
#pragma unroll
            for (int mt = 0; mt < 4; mt++)
#pragma unroll
                for (int nt = 0; nt < 4; nt++)
                    acc[mt][nt] = __builtin_amdgcn_mfma_f32_16x16x32_bf16(
                        af[mt], bfr[nt], acc[mt][nt], 0, 0, 0);
        }
    }
#pragma unroll
    for (int mt = 0; mt < 4; mt++) {
#pragma unroll
        for (int nt = 0; nt < 4; nt++) {
#pragma unroll
            for (int r = 0; r < 4; r++) {
                int row = m0 + wm + mt * 16 + quad * 4 + r;
                int col = n0 + wn + nt * 16 + c;
                float v = acc[mt][nt][r] + bias[row]
                        + resid[(long)bz * ((long)M * N) + (long)row * N + col];
                C[(long)bz * ((long)M * N) + (long)row * N + col] = v;
            }
        }
    }
}

// ---------------------------------------------------------------------------
// Flash attention v6 = R6-best (v4) MINUS s_setprio.  64 i-rows/wave,
// 3-buffer K/V counted-vmcnt pipeline, phase-merged QK, SM/PV interleave.
// setprio removed to test priority-inversion theory (softmax chain at prio 0
// starved by other waves' prio-1 MFMA clusters -> wave-serialization).
// LDS 48 KB; grid 512; XCD-grouped decode.
// ---------------------------------------------------------------------------
__global__ __launch_bounds__(256, 2) void attn_kernel(
    const bf16* QT, const bf16* __restrict__ KT,
    const bf16* __restrict__ V, bf16* AOT)
{
    const int nblk = blockIdx.x;
    const int s = nblk >> 3;
    const int it = s & 3;                          // 4 i-blocks of 256 rows
    const int g = ((s >> 2) << 3) | (nblk & 7);    // (b,h) group in [0,128)
    const int h = g & 7, b = g >> 3;
    const int i0 = it * 256;
    __shared__ __attribute__((aligned(16))) bf16 lk[3][64][64];
    __shared__ __attribute__((aligned(16))) bf16 lv[3][64][64];
    const int t = threadIdx.x, wave = t >> 6, lane = t & 63;
    const int m31 = lane & 31, hi = lane >> 5;
    const int rIS = lane >> 3, chG = (lane & 7) ^ rIS;
    // Q -> regs, B-frag layout: lane holds Q[i = iq*32+m31][k = ks*16+hi*8+e]
    v8s qf[2][4];
#pragma unroll
    for (int iq = 0; iq < 2; iq++) {
        const bf16* Qb = QT + ((long)b * 1024 + i0 + wave * 64 + iq * 32 + m31) * 512 + h * 64;
#pragma unroll
        for (int ks = 0; ks < 4; ks++)
            qf[iq][ks] = *(const v8s*)(Qb + ks * 16 + hi * 8);
    }
    // K/V staging bases: 8 segments each, 2 per wave (source-side XOR swizzle)
    const bf16* Kg[2]; const bf16* Vg[2];
#pragma unroll
    for (int j = 0; j < 2; j++) {
        int seg = wave * 2 + j;
        Kg[j] = KT + ((long)b * 1024 + seg * 8 + rIS) * 512 + h * 64 + chG * 8;
        Vg[j] = V + ((long)b * 512 + h * 64 + seg * 8 + rIS) * 1024 + chG * 8;
    }
    auto issue = [&](int jtx, int bi) {
#pragma unroll
        for (int j = 0; j < 2; j++) {
            int seg = wave * 2 + j;
            gll16(Kg[j] + (long)jtx * 64 * 512, &lk[bi][seg * 8][0]);
            gll16(Vg[j] + (long)jtx * 64,      &lv[bi][seg * 8][0]);
        }
    };
    // prologue: 2-deep prefetch (8 gll in flight per wave)
    issue(0, 0);
    issue(1, 1);
    float lsum0 = 0.f, lsum1 = 0.f;
    v16f o00 = {}, o01 = {}, o10 = {}, o11 = {};   // [iq][d-block]

// SM(jb) + PV(jb): consumes sj0 (iq0), sj1 (iq1) S^T regs for one j-half.
#define SMPV(sj0, sj1, JB)                                                     \
    {                                                                          \
        unsigned u0[8], u1[8];                                                 \
        _Pragma("unroll")                                                      \
        for (int k2 = 0; k2 < 8; k2++) {                                       \
            float p0l = __builtin_amdgcn_exp2f(sj0[2 * k2]);                   \
            float p0h = __builtin_amdgcn_exp2f(sj0[2 * k2 + 1]);               \
            float p1l = __builtin_amdgcn_exp2f(sj1[2 * k2]);                   \
            float p1h = __builtin_amdgcn_exp2f(sj1[2 * k2 + 1]);               \
            lsum0 += p0l + p0h; lsum1 += p1l + p1h;                            \
            u0[k2] = cvtpk(p0l, p0h); u1[k2] = cvtpk(p1l, p1h);                \
        }                                                                      \
        pl32swap(u0[0], u0[2]); pl32swap(u0[1], u0[3]);                        \
        pl32swap(u0[4], u0[6]); pl32swap(u0[5], u0[7]);                        \
        pl32swap(u1[0], u1[2]); pl32swap(u1[1], u1[3]);                        \
        pl32swap(u1[4], u1[6]); pl32swap(u1[5], u1[7]);                        \
        _Pragma("unroll")                                                      \
        for (int kk = 0; kk < 2; kk++) {                                       \
            union { unsigned w[4]; v8s v; } pf0, pf1;                          \
            pf0.w[0] = u0[4 * kk + 0]; pf0.w[1] = u0[4 * kk + 1];              \
            pf0.w[2] = u0[4 * kk + 2]; pf0.w[3] = u0[4 * kk + 3];              \
            pf1.w[0] = u1[4 * kk + 0]; pf1.w[1] = u1[4 * kk + 1];              \
            pf1.w[2] = u1[4 * kk + 2]; pf1.w[3] = u1[4 * kk + 3];              \
            const int cc2 = ((JB) * 2 + kk) * 2 + hi;                          \
            v8s vf0 = *(const v8s*)&lv[cur][m31][(cc2 ^ (m31 & 7)) * 8];       \
            o00 = __builtin_amdgcn_mfma_f32_32x32x16_bf16(vf0, pf0.v, o00, 0, 0, 0); \
            o10 = __builtin_amdgcn_mfma_f32_32x32x16_bf16(vf0, pf1.v, o10, 0, 0, 0); \
            v8s vf1 = *(const v8s*)&lv[cur][32 + m31][(cc2 ^ (m31 & 7)) * 8];  \
            o01 = __builtin_amdgcn_mfma_f32_32x32x16_bf16(vf1, pf0.v, o01, 0, 0, 0); \
            o11 = __builtin_amdgcn_mfma_f32_32x32x16_bf16(vf1, pf1.v, o11, 0, 0, 0); \
        }                                                                      \
    }

    for (int jt = 0; jt < 16; jt++) {
        const int cur = jt % 3;
        // counted wait: jt's 4 loads (oldest) done; jt+1's 4 stay in flight
        asm volatile("s_waitcnt vmcnt(4)" ::: "memory");
        __builtin_amdgcn_s_barrier();
        __builtin_amdgcn_sched_barrier(0);
        // prefetch jt+2 into buf[(jt+2)%3] (last read at iter jt-1; safe past
        // the barrier).  Wraparound keeps 8 in flight so vmcnt(4) stays exact.
        issue((jt + 2) & 15, (jt + 2) % 3);
        // ---- QK both j-halves: 8 independent MFMA chains ----
        v16f s00 = {}, s01 = {}, s10 = {}, s11 = {};
#pragma unroll
        for (int ks = 0; ks < 4; ks++) {
            const int chs = ((ks * 2 + hi) ^ (m31 & 7)) * 8;
            v8s kf0 = *(const v8s*)&lk[cur][m31][chs];
            v8s kf1 = *(const v8s*)&lk[cur][32 + m31][chs];
            s00 = __builtin_amdgcn_mfma_f32_32x32x16_bf16(kf0, qf[0][ks], s00, 0, 0, 0);
            s01 = __builtin_amdgcn_mfma_f32_32x32x16_bf16(kf0, qf[1][ks], s01, 0, 0, 0);
            s10 = __builtin_amdgcn_mfma_f32_32x32x16_bf16(kf1, qf[0][ks], s10, 0, 0, 0);
            s11 = __builtin_amdgcn_mfma_f32_32x32x16_bf16(kf1, qf[1][ks], s11, 0, 0, 0);
        }
        // ---- SM0 -> PV0 -> SM1 -> PV1 (SM1 fills PV0's MFMA shadow) ----
        SMPV(s00, s01, 0)
        SMPV(s10, s11, 1)
    }
#undef SMPV
    // epilogue: combine half-wave partial sums, normalize, store
    {
        float lt0 = lsum0 + __shfl_xor(lsum0, 32);
        float lt1 = lsum1 + __shfl_xor(lsum1, 32);
        float inv0 = 1.f / lt0, inv1 = 1.f / lt1;
#pragma unroll
        for (int iq = 0; iq < 2; iq++) {
            float inv = iq ? inv1 : inv0;
            const v16f& oa = iq ? o10 : o00;
            const v16f& ob = iq ? o11 : o01;
            bf16* Ob = AOT + ((long)b * 1024 + i0 + wave * 64 + iq * 32 + m31) * 512 + h * 64;
#pragma unroll
            for (int gq = 0; gq < 4; gq++) {
                union { short4 s4v; bf16 hh[4]; } w0, w1;
#pragma unroll
                for (int k = 0; k < 4; k++) {
                    w0.hh[k] = f2b(oa[gq * 4 + k] * inv);
                    w1.hh[k] = f2b(ob[gq * 4 + k] * inv);
                }
                *(short4*)(Ob + gq * 8 + hi * 4)      = w0.s4v;
                *(short4*)(Ob + 32 + gq * 8 + hi * 4) = w1.s4v;
            }
        }
    }
}

// ---------------------------------------------------------------------------
extern "C" void kernel_launch(void* const* d_in, const int* in_sizes, int n_in,
                              void* d_out, int out_size, void* d_ws, size_t ws_size,
                              hipStream_t stream)
{
    const float* x    = (const float*)d_in[0];
    const float* ctx  = (const float*)d_in[1];
    const float* nqw  = (const float*)d_in[2];
    const float* nqb  = (const float*)d_in[3];
    const float* nkw  = (const float*)d_in[4];
    const float* nkb  = (const float*)d_in[5];
    const float* cqw  = (const float*)d_in[6];
    const float* cqb  = (const float*)d_in[7];
    const float* ckvw = (const float*)d_in[8];
    const float* ckvb = (const float*)d_in[9];
    const float* pw   = (const float*)d_in[10];
    const float* pb   = (const float*)d_in[11];
    float* out = (float*)d_out;
    bf16* ws  = (bf16*)d_ws;

    const long PB  = 512L * 1024;     // per-batch elements
    const long TOT = 16L * PB;        // per-tensor elements (16 MiB bf16)
    bf16* s0 = ws;                    // xnT [b][l][c]
    bf16* s1 = ws + TOT;              // cnT [b][l][c]
    bf16* s2 = ws + 2 * TOT;          // QT; attn writes AOT in place
    bf16* s3 = ws + 3 * TOT;          // KT
    bf16* s4 = ws + 4 * TOT;          // V [b][o][l]
    bf16* wQ  = ws + 5 * TOT;         // 262144
    bf16* wKV = wQ + 262144;          // 524288
    bf16* wP  = wKV + 524288;         // 262144
    // ws use: 80 MiB + 2 MiB

    dim3 blk(256);
    gn_t_kernel<<<dim3(32, 16, 2), blk, 0, stream>>>(
        x, ctx, nqw, nqb, nkw, nkb, s0, s1);
    wconv_kernel<<<dim3(1024), blk, 0, stream>>>(cqw, ckvw, pw, wQ, wKV, wP);
    // fused Q/K/V GEMMs; 1536 blocks, XCD-grouped 1D decode
    qkv_gemm_kernel<<<dim3(1536), blk, 0, stream>>>(
        s0, s1, wQ, wKV, s2, s3, s4, cqb, ckvb);
    // attention (AOT in place over QT); 512 blocks, XCD-grouped decode
    attn_kernel<<<dim3(512), blk, 0, stream>>>(s2, s3, s4, s2);
    // out[b][o][l] = wP·AOT^T + pb + x   (fp32); 512 blocks, XCD-pinned
    gemm_proj_kernel<<<dim3(512), blk, 0, stream>>>(
        wP, s2, PB, out, pb, x, 512, 1024);
}

// Round 9
// 230.689 us; speedup vs baseline: 1.0659x; 1.0278x over previous
//
#include <hip/hip_runtime.h>
#include <hip/hip_bf16.h>

typedef short v8s __attribute__((ext_vector_type(8)));
typedef float v4f __attribute__((ext_vector_type(4)));
typedef float v16f __attribute__((ext_vector_type(16)));
typedef __hip_bfloat16 bf16;

__device__ __forceinline__ float b2f(bf16 h) { return __bfloat162float(h); }
__device__ __forceinline__ bf16 f2b(float f) { return __float2bfloat16(f); }

// Q pre-scale: hd^-0.5 * log2(e) so softmax runs in exp2 domain with no muls.
#define QSCALE 0.18033688f

// Async global->LDS, 16 B/lane; dest = lds base + lane*16 (wave-uniform base).
__device__ __forceinline__ void gll16(const void* g, void* l) {
    __builtin_amdgcn_global_load_lds(
        (const __attribute__((address_space(1))) void*)g,
        (__attribute__((address_space(3))) void*)l, 16, 0, 0);
}

// Pack two f32 -> one u32 of 2 bf16 (src0 -> low16, src1 -> high16).
__device__ __forceinline__ unsigned cvtpk(float lo, float hi_) {
    unsigned r;
    asm("v_cvt_pk_bf16_f32 %0, %1, %2" : "=v"(r) : "v"(lo), "v"(hi_));
    return r;
}

// v_permlane32_swap_b32: a[32:63] <-> b[0:31].
// After: a = [a_lo | b_lo], b = [a_hi | b_hi].
__device__ __forceinline__ void pl32swap(unsigned& a, unsigned& b) {
    asm("v_permlane32_swap_b32 %0, %1" : "+v"(a), "+v"(b));
}

// ---------------------------------------------------------------------------
// Fused GroupNorm + transpose, BOTH tensors in one dispatch (z selects).
// Reads fp32 src[b][c][l], writes bf16 dstT[b][l][c].  One block per (b,g,z).
// ---------------------------------------------------------------------------
__global__ __launch_bounds__(256) void gn_t_kernel(
    const float* __restrict__ x, const float* __restrict__ ctx,
    const float* __restrict__ qw, const float* __restrict__ qb,
    const float* __restrict__ kw, const float* __restrict__ kb,
    bf16* __restrict__ xnT, bf16* __restrict__ cnT)
{
    const int b = blockIdx.y, g = blockIdx.x, z = blockIdx.z, c0 = g * 16;
    const float* src = z ? ctx : x;
    const float* gw  = z ? kw : qw;
    const float* gb  = z ? kb : qb;
    bf16* dst = z ? cnT : xnT;
    __shared__ __attribute__((aligned(16))) bf16 lx[16][1032];
    __shared__ float rS[4], rQ[4];
    __shared__ float sSc[16], sSh[16];
    const int t = threadIdx.x, wave = t >> 6, lane = t & 63;
    const float* xb = src + ((long)b * 512 + c0) * 1024;
    float sum = 0.f, sq = 0.f;
#pragma unroll
    for (int i = 0; i < 16; i++) {
        int q = t + i * 256;              // 4096 float4s over 16x1024
        int ci = q >> 8, l0 = (q & 255) * 4;
        float4 v = *(const float4*)(xb + (long)ci * 1024 + l0);
        sum += v.x + v.y + v.z + v.w;
        sq  += v.x * v.x + v.y * v.y + v.z * v.z + v.w * v.w;
        union { short4 s4v; bf16 h[4]; } w;
        w.h[0] = f2b(v.x); w.h[1] = f2b(v.y); w.h[2] = f2b(v.z); w.h[3] = f2b(v.w);
        *(short4*)&lx[ci][l0] = w.s4v;
    }
#pragma unroll
    for (int off = 32; off > 0; off >>= 1) {
        sum += __shfl_down(sum, off);
        sq  += __shfl_down(sq, off);
    }
    if (lane == 0) { rS[wave] = sum; rQ[wave] = sq; }
    __syncthreads();
    if (t < 16) {
        float S = rS[0] + rS[1] + rS[2] + rS[3];
        float Q = rQ[0] + rQ[1] + rQ[2] + rQ[3];
        const float inv_n = 1.f / 16384.f;
        float mean = S * inv_n;
        float var  = Q * inv_n - mean * mean;
        float rstd = rsqrtf(var + 1e-5f);
        float w = gw[c0 + t];
        sSc[t] = rstd * w;
        sSh[t] = gb[c0 + t] - mean * rstd * w;
    }
    __syncthreads();
    // output: thread owns channel-half hf (8 ch) x 8 l; vector LDS reads +
    // in-register transpose.
    {
        const int hf = t & 1, lg = t >> 1;
        const int ch0 = hf * 8, l0 = lg * 8;
        v8s rd[8];
#pragma unroll
        for (int r = 0; r < 8; r++)
            rd[r] = *(const v8s*)&lx[ch0 + r][l0];
        float sc[8], sh[8];
#pragma unroll
        for (int r = 0; r < 8; r++) { sc[r] = sSc[ch0 + r]; sh[r] = sSh[ch0 + r]; }
#pragma unroll
        for (int j = 0; j < 8; j++) {
            union { float4 f4; bf16 h[8]; } o_;
#pragma unroll
            for (int r = 0; r < 8; r++) {
                union { short s; bf16 h; } cv; cv.s = rd[r][j];
                o_.h[r] = f2b(b2f(cv.h) * sc[r] + sh[r]);
            }
            *(float4*)(dst + ((long)b * 1024 + l0 + j) * 512 + c0 + ch0) = o_.f4;
        }
    }
}

// ---------------------------------------------------------------------------
// Weight fp32 -> bf16 conversion (cqw 256K, ckvw 512K, pw 256K elements).
// ---------------------------------------------------------------------------
__global__ __launch_bounds__(256) void wconv_kernel(
    const float* __restrict__ a, const float* __restrict__ bsrc,
    const float* __restrict__ csrc, bf16* __restrict__ oa,
    bf16* __restrict__ ob, bf16* __restrict__ oc)
{
    int id = blockIdx.x * 256 + threadIdx.x;     // [0, 262144) float4 units
    const float* src; bf16* dst; int off;
    if (id < 65536)       { src = a;    dst = oa; off = id; }
    else if (id < 196608) { src = bsrc; dst = ob; off = id - 65536; }
    else                  { src = csrc; dst = oc; off = id - 196608; }
    float4 v = ((const float4*)src)[off];
    union { short4 s4v; bf16 h[4]; } w;
    w.h[0] = f2b(v.x); w.h[1] = f2b(v.y); w.h[2] = f2b(v.z); w.h[3] = f2b(v.w);
    ((short4*)dst)[off] = w.s4v;
}

// ---------------------------------------------------------------------------
// Fused Q/K/V GEMM v4 = v3 (BK=32, 3-buffer counted-vmcnt pipeline, XCD-
// pinned decode) + LDS-staged COALESCED epilogue: the old per-lane 2B
// global_store_short scatter (64/thread, 48 MB total) becomes an LDS
// round-trip + 8 float4 stores/thread (fully coalesced 256B/row segments).
// Staging buffers are reused for the output tile after a vmcnt(0) drain.
// ---------------------------------------------------------------------------
__global__ __launch_bounds__(256) void qkv_gemm_kernel(
    const bf16* __restrict__ xnT, const bf16* __restrict__ cnT,
    const bf16* __restrict__ wQ, const bf16* __restrict__ wKV,
    bf16* __restrict__ QT, bf16* __restrict__ KT, bf16* __restrict__ Vo,
    const float* __restrict__ cqb, const float* __restrict__ ckvb)
{
    const long PB = 512L * 1024;
    const int blk = blockIdx.x;
    const int xcd = blk & 7, idx = blk >> 3;       // idx in [0,192)
    const int half = idx / 96, rr = idx % 96;
    const int op = rr >> 5, bx = rr & 31;          // 3 ops x 32 tiles
    const int bz = xcd + 8 * half;                 // batch pinned to xcd
    const bf16* A; const bf16* B; bf16* C; const float* bias;
    int nBlkN, N, biasPerM; float scale;
    if (op == 0) {
        A = xnT + bz * PB; B = wQ;  C = QT + bz * PB; bias = cqb;
        nBlkN = 4; N = 512; biasPerM = 0; scale = QSCALE;
    } else if (op == 1) {
        A = cnT + bz * PB; B = wKV; C = KT + bz * PB; bias = ckvb;
        nBlkN = 4; N = 512; biasPerM = 0; scale = 1.0f;
    } else {
        A = wKV + 512L * 512; B = cnT + bz * PB; C = Vo + bz * PB; bias = ckvb + 512;
        nBlkN = 8; N = 1024; biasPerM = 1; scale = 1.0f;
    }
    const int m0 = (bx / nBlkN) * 128, n0 = (bx % nBlkN) * 128;
    __shared__ __attribute__((aligned(16))) char sm[49152];
    bf16 (*lA)[128][32] = (bf16(*)[128][32])sm;             // 3 x 8 KB
    bf16 (*lB)[128][32] = (bf16(*)[128][32])(sm + 24576);   // 3 x 8 KB
    const int t = threadIdx.x, wave = t >> 6, lane = t & 63;
    const int quad = lane >> 4, c = lane & 15;
    const int wm = (wave >> 1) * 64, wn = (wave & 1) * 64;
    // staging: 8 segments of 16 rows; wave handles segs wave*2, wave*2+1
    const int r16 = lane >> 2;                     // row within segment
    const int c4 = lane & 3;                       // physical chunk
    const int cswz = c4 ^ (r16 & 3) ^ ((r16 >> 2) & 1);  // logical chunk
    const bf16* Ag[2]; const bf16* Bg[2];
#pragma unroll
    for (int j = 0; j < 2; j++) {
        int seg = wave * 2 + j;
        Ag[j] = A + (long)(m0 + seg * 16 + r16) * 512 + cswz * 8;
        Bg[j] = B + (long)(n0 + seg * 16 + r16) * 512 + cswz * 8;
    }
    auto issue = [&](int k0, int bi) {
#pragma unroll
        for (int j = 0; j < 2; j++) {
            gll16(Ag[j] + k0, &lA[bi][(wave * 2 + j) * 16][0]);
            gll16(Bg[j] + k0, &lB[bi][(wave * 2 + j) * 16][0]);
        }
    };
    v4f acc[4][4] = {};
    issue(0, 0);          // 2-deep prologue: 8 loads in flight per wave
    issue(32, 1);
    const int rdsw = (quad ^ (c & 3) ^ ((c >> 2) & 1)) * 8;  // read chunk
    for (int kc = 0; kc < 16; kc++) {
        const int cur = kc % 3;
        // retire step kc's 4 loads (issued 2 steps ago); keep kc+1's in flight
        asm volatile("s_waitcnt vmcnt(4)" ::: "memory");
        __builtin_amdgcn_s_barrier();
        __builtin_amdgcn_sched_barrier(0);
        // prefetch kc+2 (wraps redundantly at 16,17 -> keeps vmcnt exact)
        issue(((kc + 2) & 15) * 32, (kc + 2) % 3);
        v8s af[4], bfr[4];
#pragma unroll
        for (int mt = 0; mt < 4; mt++)
            af[mt] = *(const v8s*)&lA[cur][wm + mt * 16 + c][rdsw];
#pragma unroll
        for (int nt = 0; nt < 4; nt++)
            bfr[nt] = *(const v8s*)&lB[cur][wn + nt * 16 + c][rdsw];
#pragma unroll
        for (int mt = 0; mt < 4; mt++)
#pragma unroll
            for (int nt = 0; nt < 4; nt++)
                acc[mt][nt] = __builtin_amdgcn_mfma_f32_16x16x32_bf16(
                    af[mt], bfr[nt], acc[mt][nt], 0, 0, 0);
    }
    // ---- staged coalesced epilogue ----
    // drain the wraparound prefetches still writing lA/lB, then reuse as lC
    asm volatile("s_waitcnt vmcnt(0)" ::: "memory");
    __syncthreads();
    bf16 (*lC)[136] = (bf16(*)[136])sm;           // 128 x 136 = 34 KB
#pragma unroll
    for (int mt = 0; mt < 4; mt++) {
#pragma unroll
        for (int nt = 0; nt < 4; nt++) {
#pragma unroll
            for (int r = 0; r < 4; r++) {
                int row = wm + mt * 16 + quad * 4 + r;
                int col = wn + nt * 16 + c;
                float v = (acc[mt][nt][r]
                           + (biasPerM ? bias[m0 + row] : bias[n0 + col])) * scale;
                lC[row][col] = f2b(v);
            }
        }
    }
    __syncthreads();
#pragma unroll
    for (int i = 0; i < 8; i++) {
        int id = t + i * 256;                     // 2048 chunks of 16 B
        int row = id >> 4, ch = id & 15;
        float4 v4 = *(const float4*)&lC[row][ch * 8];
        *(float4*)(C + (long)(m0 + row) * N + n0 + ch * 8) = v4;
    }
}

// ---------------------------------------------------------------------------
// Projection GEMM v3: out[b][o][l] = pw·AOT^T + pb + x (fp32 out + resid).
// 2-phase double-buffer + XCD-pinned decode (R6) + LDS-staged coalesced
// epilogue: the old 128 scalar 4B VMEM ops/thread (64 resid loads + 64 out
// stores over 128 MB) become 16 float4 loads + 16 float4 stores/thread.
// Staging LDS (64 KB) is reused as the fp32 output tile [128][128].
// ---------------------------------------------------------------------------
__global__ __launch_bounds__(256) void gemm_proj_kernel(
    const bf16* __restrict__ A,
    const bf16* __restrict__ B, long sBb,
    float* __restrict__ C,
    const float* __restrict__ bias,
    const float* __restrict__ resid,
    int M, int N)
{
    const int blk = blockIdx.x;
    const int xcd = blk & 7, idx = blk >> 3;       // idx in [0,64)
    const int bz = xcd + 8 * (idx & 1);            // batch pinned to xcd
    const int tile = idx >> 1;                     // [0,32): 4 m x 8 n
    const int m0 = (tile >> 3) * 128, n0 = (tile & 7) * 128;
    const bf16* Bb = B + (long)bz * sBb;
    __shared__ __attribute__((aligned(16))) char sm[65536];
    bf16 (*lA)[128][64] = (bf16(*)[128][64])sm;             // 2 x 16 KB
    bf16 (*lB)[128][64] = (bf16(*)[128][64])(sm + 32768);   // 2 x 16 KB
    const int t = threadIdx.x, wave = t >> 6, lane = t & 63;
    const int quad = lane >> 4, c = lane & 15;
    const int wm = (wave >> 1) * 64, wn = (wave & 1) * 64;
    const int rIS = lane >> 3, chG = (lane & 7) ^ rIS;
    const bf16* Ag[4]; const bf16* Bg[4]; int segr[4];
#pragma unroll
    for (int j = 0; j < 4; j++) {
        int seg = wave + j * 4;
        segr[j] = seg * 8;
        Ag[j] = A + (long)(m0 + segr[j] + rIS) * 512 + chG * 8;
        Bg[j] = Bb + (long)(n0 + segr[j] + rIS) * 512 + chG * 8;
    }
    auto issue = [&](int k0, int bi) {
#pragma unroll
        for (int j = 0; j < 4; j++) {
            gll16(Ag[j] + k0, &lA[bi][segr[j]][0]);
            gll16(Bg[j] + k0, &lB[bi][segr[j]][0]);
        }
    };
    v4f acc[4][4] = {};
    issue(0, 0);
    for (int kc = 0; kc < 8; kc++) {
        const int cur = kc & 1;
        asm volatile("s_waitcnt vmcnt(0)" ::: "memory");
        __builtin_amdgcn_s_barrier();
        __builtin_amdgcn_sched_barrier(0);
        if (kc < 7) issue((kc + 1) * 64, cur ^ 1);
#pragma unroll
        for (int kk = 0; kk < 2; kk++) {
            v8s af[4], bfr[4];
#pragma unroll
            for (int mt = 0; mt < 4; mt++)
                af[mt] = *(const v8s*)&lA[cur][wm + mt * 16 + c][((kk * 4 + quad) ^ (c & 7)) * 8];
#pragma unroll
            for (int nt = 0; nt < 4; nt++)
                bfr[nt] = *(const v8s*)&lB[cur][wn + nt * 16 + c][((kk * 4 + quad) ^ (c & 7)) * 8];
#pragma unroll
            for (int mt = 0; mt < 4; mt++)
#pragma unroll
                for (int nt = 0; nt < 4; nt++)
                    acc[mt][nt] = __builtin_amdgcn_mfma_f32_16x16x32_bf16(
                        af[mt], bfr[nt], acc[mt][nt], 0, 0, 0);
        }
    }
    // ---- staged coalesced epilogue (nothing in flight after last iter) ----
    __syncthreads();
    float (*lC)[128] = (float(*)[128])sm;          // 128 x 128 fp32 = 64 KB
#pragma unroll
    for (int mt = 0; mt < 4; mt++) {
#pragma unroll
        for (int nt = 0; nt < 4; nt++) {
#pragma unroll
            for (int r = 0; r < 4; r++) {
                int row = wm + mt * 16 + quad * 4 + r;
                int col = wn + nt * 16 + c;
                lC[row][col] = acc[mt][nt][r] + bias[m0 + row];
            }
        }
    }
    __syncthreads();
    const long base = (long)bz * ((long)M * N);
#pragma unroll
    for (int i = 0; i < 16; i++) {
        int id = t + i * 256;                      // 4096 chunks of 16 B
        int row = id >> 5, ch = id & 31;
        const long goff = base + (long)(m0 + row) * N + n0 + ch * 4;
        float4 v = *(const float4*)&lC[row][ch * 4];
        float4 rr4 = *(const float4*)(resid + goff);
        v.x += rr4.x; v.y += rr4.y; v.z += rr4.z; v.w += rr4.w;
        *(float4*)(C + goff) = v;
    }
}

// ---------------------------------------------------------------------------
// Flash attention v4 (R6-best, setprio RESTORED — R8 A/B showed removing it
// costs +3.5 µs): 32x32x16 swapped QK^T, in-register softmax (T12),
// 64 i-rows/wave, 3-buffer K/V counted-vmcnt pipeline, phase-merged QK.
// LDS 48 KB; grid 512; XCD-grouped decode.
// ---------------------------------------------------------------------------
__global__ __launch_bounds__(256, 2) void attn_kernel(
    const bf16* QT, const bf16* __restrict__ KT,
    const bf16* __restrict__ V, bf16* AOT)
{
    const int nblk = blockIdx.x;
    const int s = nblk >> 3;
    const int it = s & 3;                          // 4 i-blocks of 256 rows
    const int g = ((s >> 2) << 3) | (nblk & 7);    // (b,h) group in [0,128)
    const int h = g & 7, b = g >> 3;
    const int i0 = it * 256;
    __shared__ __attribute__((aligned(16))) bf16 lk[3][64][64];
    __shared__ __attribute__((aligned(16))) bf16 lv[3][64][64];
    const int t = threadIdx.x, wave = t >> 6, lane = t & 63;
    const int m31 = lane & 31, hi = lane >> 5;
    const int rIS = lane >> 3, chG = (lane & 7) ^ rIS;
    // Q -> regs, B-frag layout: lane holds Q[i = iq*32+m31][k = ks*16+hi*8+e]
    v8s qf[2][4];
#pragma unroll
    for (int iq = 0; iq < 2; iq++) {
        const bf16* Qb = QT + ((long)b * 1024 + i0 + wave * 64 + iq * 32 + m31) * 512 + h * 64;
#pragma unroll
        for (int ks = 0; ks < 4; ks++)
            qf[iq][ks] = *(const v8s*)(Qb + ks * 16 + hi * 8);
    }
    // K/V staging bases: 8 segments each, 2 per wave (source-side XOR swizzle)
    const bf16* Kg[2]; const bf16* Vg[2];
#pragma unroll
    for (int j = 0; j < 2; j++) {
        int seg = wave * 2 + j;
        Kg[j] = KT + ((long)b * 1024 + seg * 8 + rIS) * 512 + h * 64 + chG * 8;
        Vg[j] = V + ((long)b * 512 + h * 64 + seg * 8 + rIS) * 1024 + chG * 8;
    }
    auto issue = [&](int jtx, int bi) {
#pragma unroll
        for (int j = 0; j < 2; j++) {
            int seg = wave * 2 + j;
            gll16(Kg[j] + (long)jtx * 64 * 512, &lk[bi][seg * 8][0]);
            gll16(Vg[j] + (long)jtx * 64,      &lv[bi][seg * 8][0]);
        }
    };
    // prologue: 2-deep prefetch (8 gll in flight per wave)
    issue(0, 0);
    issue(1, 1);
    float lsum0 = 0.f, lsum1 = 0.f;
    v16f o00 = {}, o01 = {}, o10 = {}, o11 = {};   // [iq][d-block]

// SM(jb) + PV(jb): consumes sj0 (iq0), sj1 (iq1) S^T regs for one j-half.
#define SMPV(sj0, sj1, JB)                                                     \
    {                                                                          \
        unsigned u0[8], u1[8];                                                 \
        _Pragma("unroll")                                                      \
        for (int k2 = 0; k2 < 8; k2++) {                                       \
            float p0l = __builtin_amdgcn_exp2f(sj0[2 * k2]);                   \
            float p0h = __builtin_amdgcn_exp2f(sj0[2 * k2 + 1]);               \
            float p1l = __builtin_amdgcn_exp2f(sj1[2 * k2]);                   \
            float p1h = __builtin_amdgcn_exp2f(sj1[2 * k2 + 1]);               \
            lsum0 += p0l + p0h; lsum1 += p1l + p1h;                            \
            u0[k2] = cvtpk(p0l, p0h); u1[k2] = cvtpk(p1l, p1h);                \
        }                                                                      \
        pl32swap(u0[0], u0[2]); pl32swap(u0[1], u0[3]);                        \
        pl32swap(u0[4], u0[6]); pl32swap(u0[5], u0[7]);                        \
        pl32swap(u1[0], u1[2]); pl32swap(u1[1], u1[3]);                        \
        pl32swap(u1[4], u1[6]); pl32swap(u1[5], u1[7]);                        \
        __builtin_amdgcn_s_setprio(1);                                         \
        _Pragma("unroll")                                                      \
        for (int kk = 0; kk < 2; kk++) {                                       \
            union { unsigned w[4]; v8s v; } pf0, pf1;                          \
            pf0.w[0] = u0[4 * kk + 0]; pf0.w[1] = u0[4 * kk + 1];              \
            pf0.w[2] = u0[4 * kk + 2]; pf0.w[3] = u0[4 * kk + 3];              \
            pf1.w[0] = u1[4 * kk + 0]; pf1.w[1] = u1[4 * kk + 1];              \
            pf1.w[2] = u1[4 * kk + 2]; pf1.w[3] = u1[4 * kk + 3];              \
            const int cc2 = ((JB) * 2 + kk) * 2 + hi;                          \
            v8s vf0 = *(const v8s*)&lv[cur][m31][(cc2 ^ (m31 & 7)) * 8];       \
            o00 = __builtin_amdgcn_mfma_f32_32x32x16_bf16(vf0, pf0.v, o00, 0, 0, 0); \
            o10 = __builtin_amdgcn_mfma_f32_32x32x16_bf16(vf0, pf1.v, o10, 0, 0, 0); \
            v8s vf1 = *(const v8s*)&lv[cur][32 + m31][(cc2 ^ (m31 & 7)) * 8];  \
            o01 = __builtin_amdgcn_mfma_f32_32x32x16_bf16(vf1, pf0.v, o01, 0, 0, 0); \
            o11 = __builtin_amdgcn_mfma_f32_32x32x16_bf16(vf1, pf1.v, o11, 0, 0, 0); \
        }                                                                      \
        __builtin_amdgcn_s_setprio(0);                                         \
    }

    for (int jt = 0; jt < 16; jt++) {
        const int cur = jt % 3;
        // counted wait: jt's 4 loads (oldest) done; jt+1's 4 stay in flight
        asm volatile("s_waitcnt vmcnt(4)" ::: "memory");
        __builtin_amdgcn_s_barrier();
        __builtin_amdgcn_sched_barrier(0);
        // prefetch jt+2 into buf[(jt+2)%3] (last read at iter jt-1; safe past
        // the barrier).  Wraparound keeps 8 in flight so vmcnt(4) stays exact.
        issue((jt + 2) & 15, (jt + 2) % 3);
        // ---- QK both j-halves: 8 independent MFMA chains ----
        v16f s00 = {}, s01 = {}, s10 = {}, s11 = {};
        __builtin_amdgcn_s_setprio(1);
#pragma unroll
        for (int ks = 0; ks < 4; ks++) {
            const int chs = ((ks * 2 + hi) ^ (m31 & 7)) * 8;
            v8s kf0 = *(const v8s*)&lk[cur][m31][chs];
            v8s kf1 = *(const v8s*)&lk[cur][32 + m31][chs];
            s00 = __builtin_amdgcn_mfma_f32_32x32x16_bf16(kf0, qf[0][ks], s00, 0, 0, 0);
            s01 = __builtin_amdgcn_mfma_f32_32x32x16_bf16(kf0, qf[1][ks], s01, 0, 0, 0);
            s10 = __builtin_amdgcn_mfma_f32_32x32x16_bf16(kf1, qf[0][ks], s10, 0, 0, 0);
            s11 = __builtin_amdgcn_mfma_f32_32x32x16_bf16(kf1, qf[1][ks], s11, 0, 0, 0);
        }
        __builtin_amdgcn_s_setprio(0);
        // ---- SM0 -> PV0 -> SM1 -> PV1 (SM1 fills PV0's MFMA shadow) ----
        SMPV(s00, s01, 0)
        SMPV(s10, s11, 1)
    }
#undef SMPV
    // epilogue: combine half-wave partial sums, normalize, store
    {
        float lt0 = lsum0 + __shfl_xor(lsum0, 32);
        float lt1 = lsum1 + __shfl_xor(lsum1, 32);
        float inv0 = 1.f / lt0, inv1 = 1.f / lt1;
#pragma unroll
        for (int iq = 0; iq < 2; iq++) {
            float inv = iq ? inv1 : inv0;
            const v16f& oa = iq ? o10 : o00;
            const v16f& ob = iq ? o11 : o01;
            bf16* Ob = AOT + ((long)b * 1024 + i0 + wave * 64 + iq * 32 + m31) * 512 + h * 64;
#pragma unroll
            for (int gq = 0; gq < 4; gq++) {
                union { short4 s4v; bf16 hh[4]; } w0, w1;
#pragma unroll
                for (int k = 0; k < 4; k++) {
                    w0.hh[k] = f2b(oa[gq * 4 + k] * inv);
                    w1.hh[k] = f2b(ob[gq * 4 + k] * inv);
                }
                *(short4*)(Ob + gq * 8 + hi * 4)      = w0.s4v;
                *(short4*)(Ob + 32 + gq * 8 + hi * 4) = w1.s4v;
            }
        }
    }
}

// ---------------------------------------------------------------------------
extern "C" void kernel_launch(void* const* d_in, const int* in_sizes, int n_in,
                              void* d_out, int out_size, void* d_ws, size_t ws_size,
                              hipStream_t stream)
{
    const float* x    = (const float*)d_in[0];
    const float* ctx  = (const float*)d_in[1];
    const float* nqw  = (const float*)d_in[2];
    const float* nqb  = (const float*)d_in[3];
    const float* nkw  = (const float*)d_in[4];
    const float* nkb  = (const float*)d_in[5];
    const float* cqw  = (const float*)d_in[6];
    const float* cqb  = (const float*)d_in[7];
    const float* ckvw = (const float*)d_in[8];
    const float* ckvb = (const float*)d_in[9];
    const float* pw   = (const float*)d_in[10];
    const float* pb   = (const float*)d_in[11];
    float* out = (float*)d_out;
    bf16* ws  = (bf16*)d_ws;

    const long PB  = 512L * 1024;     // per-batch elements
    const long TOT = 16L * PB;        // per-tensor elements (16 MiB bf16)
    bf16* s0 = ws;                    // xnT [b][l][c]
    bf16* s1 = ws + TOT;              // cnT [b][l][c]
    bf16* s2 = ws + 2 * TOT;          // QT; attn writes AOT in place
    bf16* s3 = ws + 3 * TOT;          // KT
    bf16* s4 = ws + 4 * TOT;          // V [b][o][l]
    bf16* wQ  = ws + 5 * TOT;         // 262144
    bf16* wKV = wQ + 262144;          // 524288
    bf16* wP  = wKV + 524288;         // 262144
    // ws use: 80 MiB + 2 MiB

    dim3 blk(256);
    gn_t_kernel<<<dim3(32, 16, 2), blk, 0, stream>>>(
        x, ctx, nqw, nqb, nkw, nkb, s0, s1);
    wconv_kernel<<<dim3(1024), blk, 0, stream>>>(cqw, ckvw, pw, wQ, wKV, wP);
    // fused Q/K/V GEMMs; 1536 blocks, XCD-grouped 1D decode
    qkv_gemm_kernel<<<dim3(1536), blk, 0, stream>>>(
        s0, s1, wQ, wKV, s2, s3, s4, cqb, ckvb);
    // attention (AOT in place over QT); 512 blocks, XCD-grouped decode
    attn_kernel<<<dim3(512), blk, 0, stream>>>(s2, s3, s4, s2);
    // out[b][o][l] = wP·AOT^T + pb + x   (fp32); 512 blocks, XCD-pinned
    gemm_proj_kernel<<<dim3(512), blk, 0, stream>>>(
        wP, s2, PB, out, pb, x, 512, 1024);
}